// Round 1
// baseline (558.695 us; speedup 1.0000x reference)
//
#include <hip/hip_runtime.h>
#include <stdint.h>

typedef unsigned short u16;
typedef __attribute__((ext_vector_type(8))) short short8;   // 8 bf16 bits (4 VGPRs)
typedef __attribute__((ext_vector_type(4))) float f32x4;

#define M_TOK 8192
#define N_OUT 4096
#define K_IN  4096

#define BM 128
#define BN 128
#define BK 32

// global->LDS direct copy, 16B per lane. LDS dest is wave-uniform base + lane*16.
#define GLDS16(gp, lp)                                                         \
  __builtin_amdgcn_global_load_lds(                                            \
      (const __attribute__((address_space(1))) void*)(gp),                     \
      (__attribute__((address_space(3))) void*)(lp), 16, 0, 0)

__device__ inline u16 f2bf_rne(float f) {
  union { float f; uint32_t u; } v; v.f = f;
  uint32_t u = v.u;
  return (u16)((u + 0x7fffu + ((u >> 16) & 1u)) >> 16);
}

// x (fp32) -> bf16, 8 elems/thread, 16B stores
__global__ void __launch_bounds__(256) cvt_x_bf16(const float* __restrict__ in,
                                                  u16* __restrict__ out, int n8) {
  int i = blockIdx.x * 256 + threadIdx.x;
  if (i >= n8) return;
  const float4* p = (const float4*)in + (size_t)i * 2;
  float4 a = p[0], b = p[1];
  uint4 o;
  o.x = (uint32_t)f2bf_rne(a.x) | ((uint32_t)f2bf_rne(a.y) << 16);
  o.y = (uint32_t)f2bf_rne(a.z) | ((uint32_t)f2bf_rne(a.w) << 16);
  o.z = (uint32_t)f2bf_rne(b.x) | ((uint32_t)f2bf_rne(b.y) << 16);
  o.w = (uint32_t)f2bf_rne(b.z) | ((uint32_t)f2bf_rne(b.w) << 16);
  ((uint4*)out)[i] = o;
}

__device__ inline uint32_t sign2bf_pair(float x, float y) {
  uint32_t lo = x > 0.f ? 0x3F80u : (x < 0.f ? 0xBF80u : 0u); // +1 / -1 / 0 in bf16
  uint32_t hi = y > 0.f ? 0x3F80u : (y < 0.f ? 0xBF80u : 0u);
  return lo | (hi << 16);
}

// sign(W) (fp32) -> bf16 {-1,0,+1}, 8 elems/thread
__global__ void __launch_bounds__(256) cvt_w_sign(const float* __restrict__ in,
                                                  u16* __restrict__ out, int n8) {
  int i = blockIdx.x * 256 + threadIdx.x;
  if (i >= n8) return;
  const float4* p = (const float4*)in + (size_t)i * 2;
  float4 a = p[0], b = p[1];
  uint4 o;
  o.x = sign2bf_pair(a.x, a.y);
  o.y = sign2bf_pair(a.z, a.w);
  o.z = sign2bf_pair(b.x, b.y);
  o.w = sign2bf_pair(b.z, b.w);
  ((uint4*)out)[i] = o;
}

// C[m][n] = sum_k A[m][k] * B[n][k] + bias[n]
// A: M x K bf16 row-major; B: N x K bf16 row-major (NT layout, both K-contiguous)
__global__ void __launch_bounds__(256) gemm_bin_bf16(
    const u16* __restrict__ A, const u16* __restrict__ B,
    const float* __restrict__ bias, float* __restrict__ C) {
  // unpadded row-major tiles (required by global_load_lds lane-contiguous dest)
  __shared__ u16 sA[BM * BK];
  __shared__ u16 sB[BN * BK];

  const int tid  = threadIdx.x;
  const int lane = tid & 63;
  const int wv   = tid >> 6;   // 4 waves
  const int wr   = wv >> 1;    // wave row 0..1 (64 rows each)
  const int wc   = wv & 1;     // wave col 0..1 (64 cols each)

  const int m0 = blockIdx.y * BM;
  const int n0 = blockIdx.x * BN;

  // staging: wave wv covers tile rows [wv*32, wv*32+32), 2 instrs x 16 rows,
  // lane L -> row +=(L>>2), k = (L&3)*8  (16B per lane)
  const int ldRow = lane >> 2;
  const int ldK   = (lane & 3) * 8;
  const u16* gA = A + (size_t)(m0 + wv * 32 + ldRow) * K_IN + ldK;
  const u16* gB = B + (size_t)(n0 + wv * 32 + ldRow) * K_IN + ldK;
  u16* lA0 = &sA[(wv * 32 +  0) * BK];
  u16* lA1 = &sA[(wv * 32 + 16) * BK];
  u16* lB0 = &sB[(wv * 32 +  0) * BK];
  u16* lB1 = &sB[(wv * 32 + 16) * BK];

  f32x4 acc[4][4];
#pragma unroll
  for (int i = 0; i < 4; i++)
#pragma unroll
    for (int j = 0; j < 4; j++) acc[i][j] = (f32x4){0.f, 0.f, 0.f, 0.f};

  const int fragK = (lane >> 4) * 8;   // k offset within tile for A/B fragments
  const int fragR = lane & 15;         // m (or n) within 16x16 tile

  for (int k0 = 0; k0 < K_IN; k0 += BK) {
    GLDS16(gA + k0,             lA0);
    GLDS16(gA + k0 + 16 * K_IN, lA1);
    GLDS16(gB + k0,             lB0);
    GLDS16(gB + k0 + 16 * K_IN, lB1);
    __syncthreads();   // compiler emits vmcnt(0) drain before barrier

    short8 aF[4], bF[4];
#pragma unroll
    for (int mi = 0; mi < 4; mi++)
      aF[mi] = *(const short8*)&sA[(wr * 64 + mi * 16 + fragR) * BK + fragK];
#pragma unroll
    for (int ni = 0; ni < 4; ni++)
      bF[ni] = *(const short8*)&sB[(wc * 64 + ni * 16 + fragR) * BK + fragK];

#pragma unroll
    for (int mi = 0; mi < 4; mi++)
#pragma unroll
      for (int ni = 0; ni < 4; ni++)
        acc[mi][ni] = __builtin_amdgcn_mfma_f32_16x16x32_bf16(
            aF[mi], bF[ni], acc[mi][ni], 0, 0, 0);

    __syncthreads();
  }

  // epilogue: C/D layout col=lane&15, row=(lane>>4)*4+reg
#pragma unroll
  for (int ni = 0; ni < 4; ni++) {
    const int col = n0 + wc * 64 + ni * 16 + (lane & 15);
    const float bv = bias[col];
#pragma unroll
    for (int mi = 0; mi < 4; mi++) {
      const int row = m0 + wr * 64 + mi * 16 + (lane >> 4) * 4;
      float* cp = C + (size_t)row * N_OUT + col;
#pragma unroll
      for (int r = 0; r < 4; r++)
        cp[(size_t)r * N_OUT] = acc[mi][ni][r] + bv;
    }
  }
}

// emergency fallback if ws too small (correct but slow)
__global__ void fallback_gemm(const float* __restrict__ x, const float* __restrict__ w,
                              const float* __restrict__ bias, float* __restrict__ out) {
  int idx = blockIdx.x * blockDim.x + threadIdx.x;
  if (idx >= M_TOK * N_OUT) return;
  int row = idx / N_OUT, col = idx % N_OUT;
  const float* xp = x + (size_t)row * K_IN;
  const float* wp = w + (size_t)col * K_IN;
  float s = 0.f;
  for (int k = 0; k < K_IN; k++) {
    float wv = wp[k];
    float sg = wv > 0.f ? 1.f : (wv < 0.f ? -1.f : 0.f);
    s += xp[k] * sg;
  }
  out[idx] = s + bias[col];
}

extern "C" void kernel_launch(void* const* d_in, const int* in_sizes, int n_in,
                              void* d_out, int out_size, void* d_ws, size_t ws_size,
                              hipStream_t stream) {
  const float* x    = (const float*)d_in[0];
  const float* w    = (const float*)d_in[1];
  const float* bias = (const float*)d_in[2];
  float* out = (float*)d_out;

  const size_t xb_bytes = (size_t)M_TOK * K_IN * sizeof(u16);   // 64 MiB
  const size_t wb_bytes = (size_t)N_OUT * K_IN * sizeof(u16);   // 32 MiB

  if (ws_size < xb_bytes + wb_bytes) {
    int total = M_TOK * N_OUT;
    fallback_gemm<<<(total + 255) / 256, 256, 0, stream>>>(x, w, bias, out);
    return;
  }

  u16* xb = (u16*)d_ws;
  u16* wb = (u16*)((char*)d_ws + xb_bytes);

  {
    int n8 = M_TOK * K_IN / 8;
    cvt_x_bf16<<<(n8 + 255) / 256, 256, 0, stream>>>(x, xb, n8);
  }
  {
    int n8 = N_OUT * K_IN / 8;
    cvt_w_sign<<<(n8 + 255) / 256, 256, 0, stream>>>(w, wb, n8);
  }
  dim3 grid(N_OUT / BN, M_TOK / BM);  // 32 x 64 = 2048 blocks
  gemm_bin_bf16<<<grid, 256, 0, stream>>>(xb, wb, bias, out);
}

// Round 2
// 435.395 us; speedup vs baseline: 1.2832x; 1.2832x over previous
//
#include <hip/hip_runtime.h>
#include <stdint.h>

typedef __attribute__((ext_vector_type(4))) int   i32x4;

#define M_TOK 8192
#define N_OUT 4096
#define K_IN  4096

#define BM 128
#define BN 128
#define BK 64   // i8 K-tile: 64 bytes/row == same staging shape as bf16 BK=32

// global->LDS direct copy, 16B per lane. LDS dest is wave-uniform base + lane*16.
#define GLDS16(gp, lp)                                                         \
  __builtin_amdgcn_global_load_lds(                                            \
      (const __attribute__((address_space(1))) void*)(gp),                     \
      (__attribute__((address_space(3))) void*)(lp), 16, 0, 0)

// ---------------------------------------------------------------------------
// x (fp32, row-major MxK) -> i8 with per-row scale. One block per row.
// Thread t handles 16 consecutive elems (4x float4 loads, one uint4 store).
// ---------------------------------------------------------------------------
__global__ void __launch_bounds__(256) quant_x_i8(const float* __restrict__ x,
                                                  char* __restrict__ xq,
                                                  float* __restrict__ scales) {
  const int row = blockIdx.x;
  const int t   = threadIdx.x;
  const float* rp = x + (size_t)row * K_IN + t * 16;

  float v[16];
#pragma unroll
  for (int p = 0; p < 4; p++) {
    float4 f = ((const float4*)rp)[p];
    v[p * 4 + 0] = f.x; v[p * 4 + 1] = f.y; v[p * 4 + 2] = f.z; v[p * 4 + 3] = f.w;
  }
  float amax = 0.f;
#pragma unroll
  for (int i = 0; i < 16; i++) amax = fmaxf(amax, fabsf(v[i]));

  // wave64 butterfly reduce
#pragma unroll
  for (int off = 32; off > 0; off >>= 1)
    amax = fmaxf(amax, __shfl_xor(amax, off));

  __shared__ float wmax[4];
  if ((t & 63) == 0) wmax[t >> 6] = amax;
  __syncthreads();
  amax = fmaxf(fmaxf(wmax[0], wmax[1]), fmaxf(wmax[2], wmax[3]));
  amax = fmaxf(amax, 1e-30f);

  const float inv = 127.f / amax;
  if (t == 0) scales[row] = amax / 127.f;

  uint32_t o[4];
#pragma unroll
  for (int p = 0; p < 4; p++) {
    uint32_t b0 = (uint32_t)(__float2int_rn(v[p * 4 + 0] * inv) & 0xFF);
    uint32_t b1 = (uint32_t)(__float2int_rn(v[p * 4 + 1] * inv) & 0xFF);
    uint32_t b2 = (uint32_t)(__float2int_rn(v[p * 4 + 2] * inv) & 0xFF);
    uint32_t b3 = (uint32_t)(__float2int_rn(v[p * 4 + 3] * inv) & 0xFF);
    o[p] = b0 | (b1 << 8) | (b2 << 16) | (b3 << 24);
  }
  uint4 pk; pk.x = o[0]; pk.y = o[1]; pk.z = o[2]; pk.w = o[3];
  ((uint4*)(xq + (size_t)row * K_IN + t * 16))[0] = pk;
}

// ---------------------------------------------------------------------------
// sign(W) (fp32) -> i8 {-1,0,+1}. 16 elems/thread.
// ---------------------------------------------------------------------------
__global__ void __launch_bounds__(256) quant_w_sign(const float* __restrict__ w,
                                                    char* __restrict__ wq, int n16) {
  int i = blockIdx.x * 256 + threadIdx.x;
  if (i >= n16) return;
  const float4* p = (const float4*)w + (size_t)i * 4;
  uint32_t o[4];
#pragma unroll
  for (int q = 0; q < 4; q++) {
    float4 f = p[q];
    int s0 = (f.x > 0.f) - (f.x < 0.f);
    int s1 = (f.y > 0.f) - (f.y < 0.f);
    int s2 = (f.z > 0.f) - (f.z < 0.f);
    int s3 = (f.w > 0.f) - (f.w < 0.f);
    o[q] = (uint32_t)(s0 & 0xFF) | ((uint32_t)(s1 & 0xFF) << 8) |
           ((uint32_t)(s2 & 0xFF) << 16) | ((uint32_t)(s3 & 0xFF) << 24);
  }
  uint4 pk; pk.x = o[0]; pk.y = o[1]; pk.z = o[2]; pk.w = o[3];
  ((uint4*)wq)[i] = pk;
}

// ---------------------------------------------------------------------------
// C[m][n] = scale[m] * (sum_k Aq[m][k] * Wq[n][k]) + bias[n]
// Aq: MxK i8 row-major; Wq: NxK i8 row-major (NT, both K-contiguous).
// m97 structure: 128x128 tile, BK=64, 4 waves each 64x64 via 4x4 of 16x16x64.
// ---------------------------------------------------------------------------
__global__ void __launch_bounds__(256) gemm_bin_i8(
    const char* __restrict__ A, const char* __restrict__ B,
    const float* __restrict__ scales, const float* __restrict__ bias,
    float* __restrict__ C) {
  __shared__ char sA[BM * BK];   // 8 KB, unpadded (global_load_lds layout)
  __shared__ char sB[BN * BK];   // 8 KB

  const int tid  = threadIdx.x;
  const int lane = tid & 63;
  const int wv   = tid >> 6;
  const int wr   = wv >> 1;    // wave row 0..1 (64 rows)
  const int wc   = wv & 1;     // wave col 0..1 (64 cols)

  const int m0 = blockIdx.y * BM;
  const int n0 = blockIdx.x * BN;

  // staging: wave wv covers tile rows [wv*32, wv*32+32); lane L -> row += L>>2,
  // byte-k = (L&3)*16  (4 lanes x 16B = 64 B/row)
  const int ldRow = lane >> 2;
  const int ldK   = (lane & 3) * 16;
  const char* gA = A + (size_t)(m0 + wv * 32 + ldRow) * K_IN + ldK;
  const char* gB = B + (size_t)(n0 + wv * 32 + ldRow) * K_IN + ldK;
  char* lA0 = &sA[(wv * 32 +  0) * BK];
  char* lA1 = &sA[(wv * 32 + 16) * BK];
  char* lB0 = &sB[(wv * 32 +  0) * BK];
  char* lB1 = &sB[(wv * 32 + 16) * BK];

  i32x4 acc[4][4];
#pragma unroll
  for (int i = 0; i < 4; i++)
#pragma unroll
    for (int j = 0; j < 4; j++) acc[i][j] = (i32x4){0, 0, 0, 0};

  const int fragK = (lane >> 4) * 16;  // byte offset within row (16 i8 per lane)
  const int fragR = lane & 15;

  for (int k0 = 0; k0 < K_IN; k0 += BK) {
    GLDS16(gA + k0,             lA0);
    GLDS16(gA + k0 + 16 * K_IN, lA1);
    GLDS16(gB + k0,             lB0);
    GLDS16(gB + k0 + 16 * K_IN, lB1);
    __syncthreads();

    i32x4 aF[4], bF[4];
#pragma unroll
    for (int mi = 0; mi < 4; mi++)
      aF[mi] = *(const i32x4*)&sA[(wr * 64 + mi * 16 + fragR) * BK + fragK];
#pragma unroll
    for (int ni = 0; ni < 4; ni++)
      bF[ni] = *(const i32x4*)&sB[(wc * 64 + ni * 16 + fragR) * BK + fragK];

#pragma unroll
    for (int mi = 0; mi < 4; mi++)
#pragma unroll
      for (int ni = 0; ni < 4; ni++)
        acc[mi][ni] = __builtin_amdgcn_mfma_i32_16x16x64_i8(
            aF[mi], bF[ni], acc[mi][ni], 0, 0, 0);

    __syncthreads();
  }

  // epilogue: C/D layout col=lane&15, row=(lane>>4)*4+reg (dtype-independent)
#pragma unroll
  for (int ni = 0; ni < 4; ni++) {
    const int col = n0 + wc * 64 + ni * 16 + (lane & 15);
    const float bv = bias[col];
#pragma unroll
    for (int mi = 0; mi < 4; mi++) {
      const int row0 = m0 + wr * 64 + mi * 16 + (lane >> 4) * 4;
      float* cp = C + (size_t)row0 * N_OUT + col;
#pragma unroll
      for (int r = 0; r < 4; r++)
        cp[(size_t)r * N_OUT] = (float)acc[mi][ni][r] * scales[row0 + r] + bv;
    }
  }
}

// emergency fallback if ws too small (correct but slow)
__global__ void fallback_gemm(const float* __restrict__ x, const float* __restrict__ w,
                              const float* __restrict__ bias, float* __restrict__ out) {
  int idx = blockIdx.x * blockDim.x + threadIdx.x;
  if (idx >= M_TOK * N_OUT) return;
  int row = idx / N_OUT, col = idx % N_OUT;
  const float* xp = x + (size_t)row * K_IN;
  const float* wp = w + (size_t)col * K_IN;
  float s = 0.f;
  for (int k = 0; k < K_IN; k++) {
    float wv = wp[k];
    float sg = wv > 0.f ? 1.f : (wv < 0.f ? -1.f : 0.f);
    s += xp[k] * sg;
  }
  out[idx] = s + bias[col];
}

extern "C" void kernel_launch(void* const* d_in, const int* in_sizes, int n_in,
                              void* d_out, int out_size, void* d_ws, size_t ws_size,
                              hipStream_t stream) {
  const float* x    = (const float*)d_in[0];
  const float* w    = (const float*)d_in[1];
  const float* bias = (const float*)d_in[2];
  float* out = (float*)d_out;

  const size_t xq_bytes = (size_t)M_TOK * K_IN;           // 32 MiB
  const size_t wq_bytes = (size_t)N_OUT * K_IN;           // 16 MiB
  const size_t sc_bytes = (size_t)M_TOK * sizeof(float);  // 32 KiB

  if (ws_size < xq_bytes + wq_bytes + sc_bytes) {
    int total = M_TOK * N_OUT;
    fallback_gemm<<<(total + 255) / 256, 256, 0, stream>>>(x, w, bias, out);
    return;
  }

  char*  xq = (char*)d_ws;
  char*  wq = (char*)d_ws + xq_bytes;
  float* sc = (float*)((char*)d_ws + xq_bytes + wq_bytes);

  quant_x_i8<<<M_TOK, 256, 0, stream>>>(x, xq, sc);
  {
    int n16 = N_OUT * K_IN / 16;
    quant_w_sign<<<(n16 + 255) / 256, 256, 0, stream>>>(w, wq, n16);
  }
  dim3 grid(N_OUT / BN, M_TOK / BM);  // 32 x 64 = 2048 blocks
  gemm_bin_i8<<<grid, 256, 0, stream>>>(xq, wq, sc, bias, out);
}

// Round 3
// 405.124 us; speedup vs baseline: 1.3791x; 1.0747x over previous
//
#include <hip/hip_runtime.h>
#include <stdint.h>

typedef __attribute__((ext_vector_type(4)))  int i32x4;
typedef __attribute__((ext_vector_type(16))) int i32x16;

#define M_TOK 8192
#define N_OUT 4096
#define K_IN  4096

#define BM 128
#define BN 128
#define BK 128   // i8: 128 B/row, 8 x 16B chunks -> full-width XOR swizzle

// global->LDS direct copy, 16B per lane. LDS dest is wave-uniform base + lane*16
// (per-lane GLOBAL gather is allowed; only the LDS side is lane-sequential).
#define GLDS16(gp, lp)                                                         \
  __builtin_amdgcn_global_load_lds(                                            \
      (const __attribute__((address_space(1))) void*)(gp),                     \
      (__attribute__((address_space(3))) void*)(lp), 16, 0, 0)

// ---------------------------------------------------------------------------
// x (fp32, row-major MxK) -> i8 with per-row scale. One block per row.
// Coalesced: thread t owns float4 indices {t, t+256, t+512, t+768}.
// ---------------------------------------------------------------------------
__global__ void __launch_bounds__(256) quant_x_i8(const float* __restrict__ x,
                                                  char* __restrict__ xq,
                                                  float* __restrict__ scales) {
  const int row = blockIdx.x;
  const int t   = threadIdx.x;
  const float4* rp = (const float4*)(x + (size_t)row * K_IN);

  float4 v[4];
#pragma unroll
  for (int p = 0; p < 4; p++) v[p] = rp[p * 256 + t];

  float amax = 0.f;
#pragma unroll
  for (int p = 0; p < 4; p++)
    amax = fmaxf(amax, fmaxf(fmaxf(fabsf(v[p].x), fabsf(v[p].y)),
                             fmaxf(fabsf(v[p].z), fabsf(v[p].w))));

#pragma unroll
  for (int off = 32; off > 0; off >>= 1)
    amax = fmaxf(amax, __shfl_xor(amax, off));

  __shared__ float wmax[4];
  if ((t & 63) == 0) wmax[t >> 6] = amax;
  __syncthreads();
  amax = fmaxf(fmaxf(wmax[0], wmax[1]), fmaxf(wmax[2], wmax[3]));
  amax = fmaxf(amax, 1e-30f);

  const float inv = 127.f / amax;
  if (t == 0) scales[row] = amax / 127.f;

  uint32_t* op = (uint32_t*)(xq + (size_t)row * K_IN);
#pragma unroll
  for (int p = 0; p < 4; p++) {
    uint32_t b0 = (uint32_t)(__float2int_rn(v[p].x * inv) & 0xFF);
    uint32_t b1 = (uint32_t)(__float2int_rn(v[p].y * inv) & 0xFF);
    uint32_t b2 = (uint32_t)(__float2int_rn(v[p].z * inv) & 0xFF);
    uint32_t b3 = (uint32_t)(__float2int_rn(v[p].w * inv) & 0xFF);
    op[p * 256 + t] = b0 | (b1 << 8) | (b2 << 16) | (b3 << 24);
  }
}

// ---------------------------------------------------------------------------
// sign(W) (fp32) -> i8 {-1,0,+1}. Coalesced, 4 float4 per thread at stride 256.
// ---------------------------------------------------------------------------
__global__ void __launch_bounds__(256) quant_w_sign(const float* __restrict__ w,
                                                    char* __restrict__ wq) {
  const int t = threadIdx.x;
  const size_t base = (size_t)blockIdx.x * 1024;  // in float4 units
  const float4* p = (const float4*)w + base;
  uint32_t* op = (uint32_t*)wq + base;
#pragma unroll
  for (int q = 0; q < 4; q++) {
    float4 f = p[q * 256 + t];
    int s0 = (f.x > 0.f) - (f.x < 0.f);
    int s1 = (f.y > 0.f) - (f.y < 0.f);
    int s2 = (f.z > 0.f) - (f.z < 0.f);
    int s3 = (f.w > 0.f) - (f.w < 0.f);
    op[q * 256 + t] = (uint32_t)(s0 & 0xFF) | ((uint32_t)(s1 & 0xFF) << 8) |
                      ((uint32_t)(s2 & 0xFF) << 16) | ((uint32_t)(s3 & 0xFF) << 24);
  }
}

// ---------------------------------------------------------------------------
// C[m][n] = scale[m] * (sum_k Aq[m][k] * Wq[n][k]) + bias[n]
// 128x128 tile, BK=128, 4 waves each 64x64 via 2x2 of mfma_i32_32x32x32_i8.
// LDS: [row][8 slots x 16B], slot s of row r holds chunk (s ^ (r&7)) -> the
// fragment ds_read_b128 pattern is bank-conflict-free (8 distinct 4-bank
// groups per half-wave).
// ---------------------------------------------------------------------------
__global__ void __launch_bounds__(256) gemm_bin_i8(
    const char* __restrict__ A, const char* __restrict__ B,
    const float* __restrict__ scales, const float* __restrict__ bias,
    float* __restrict__ C) {
  __shared__ char sA[BM * BK];   // 16 KB
  __shared__ char sB[BN * BK];   // 16 KB

  const int tid  = threadIdx.x;
  const int lane = tid & 63;
  const int wv   = tid >> 6;
  const int wr   = wv >> 1;    // wave row 0..1 (64 rows)
  const int wc   = wv & 1;     // wave col 0..1 (64 cols)

  const int m0 = blockIdx.y * BM;
  const int n0 = blockIdx.x * BN;

  // staging: wave wv stages rows [wv*32, wv*32+32), 4 GLDS16 each for A and B.
  // instr g: lane L -> row = wv*32 + g*8 + (L>>3); slot (L&7) receives
  // chunk c = (L&7) ^ (row&7) = (L&7) ^ (L>>3)   (g*8, wv*32 are ==0 mod 8)
  const int srow   = lane >> 3;
  const int schunk = (lane & 7) ^ srow;
  const char* gA = A + (size_t)(m0 + wv * 32 + srow) * K_IN + schunk * 16;
  const char* gB = B + (size_t)(n0 + wv * 32 + srow) * K_IN + schunk * 16;
  char* lA = &sA[(wv * 32) * BK];
  char* lB = &sB[(wv * 32) * BK];

  i32x16 acc[2][2];
#pragma unroll
  for (int i = 0; i < 2; i++)
#pragma unroll
    for (int j = 0; j < 2; j++)
#pragma unroll
      for (int r = 0; r < 16; r++) acc[i][j][r] = 0;

  // fragment reads: lane L -> row (L&31), k-16B-half k16 = L>>5.
  // chunk c = ks*2 + k16; stored at slot c ^ (row&7), row&7 == lane&7.
  const int fr  = lane & 31;
  const int k16 = lane >> 5;
  const int x7  = lane & 7;
  const char* rA = &sA[(wr * 64 + fr) * BK];
  const char* rB = &sB[(wc * 64 + fr) * BK];

  for (int k0 = 0; k0 < K_IN; k0 += BK) {
#pragma unroll
    for (int g = 0; g < 4; g++) {
      GLDS16(gA + k0 + (size_t)(g * 8) * K_IN, lA + g * 8 * BK);
      GLDS16(gB + k0 + (size_t)(g * 8) * K_IN, lB + g * 8 * BK);
    }
    __syncthreads();

#pragma unroll
    for (int ks = 0; ks < 4; ks++) {
      const int soff = ((ks * 2 + k16) ^ x7) << 4;
      i32x4 aF[2], bF[2];
      aF[0] = *(const i32x4*)(rA + soff);
      aF[1] = *(const i32x4*)(rA + 32 * BK + soff);
      bF[0] = *(const i32x4*)(rB + soff);
      bF[1] = *(const i32x4*)(rB + 32 * BK + soff);
#pragma unroll
      for (int mi = 0; mi < 2; mi++)
#pragma unroll
        for (int ni = 0; ni < 2; ni++)
          acc[mi][ni] = __builtin_amdgcn_mfma_i32_32x32x32_i8(
              aF[mi], bF[ni], acc[mi][ni], 0, 0, 0);
    }
    __syncthreads();
  }

  // epilogue: 32x32 C/D layout col=lane&31, row=4*(lane>>5)+8*(reg>>2)+(reg&3)
#pragma unroll
  for (int ni = 0; ni < 2; ni++) {
    const int col = n0 + wc * 64 + ni * 32 + (lane & 31);
    const float bv = bias[col];
#pragma unroll
    for (int mi = 0; mi < 2; mi++) {
      const int rbase = m0 + wr * 64 + mi * 32 + (lane >> 5) * 4;
#pragma unroll
      for (int r = 0; r < 16; r++) {
        const int row = rbase + (r & 3) + 8 * (r >> 2);
        C[(size_t)row * N_OUT + col] = (float)acc[mi][ni][r] * scales[row] + bv;
      }
    }
  }
}

// emergency fallback if ws too small (correct but slow)
__global__ void fallback_gemm(const float* __restrict__ x, const float* __restrict__ w,
                              const float* __restrict__ bias, float* __restrict__ out) {
  int idx = blockIdx.x * blockDim.x + threadIdx.x;
  if (idx >= M_TOK * N_OUT) return;
  int row = idx / N_OUT, col = idx % N_OUT;
  const float* xp = x + (size_t)row * K_IN;
  const float* wp = w + (size_t)col * K_IN;
  float s = 0.f;
  for (int k = 0; k < K_IN; k++) {
    float wv = wp[k];
    float sg = wv > 0.f ? 1.f : (wv < 0.f ? -1.f : 0.f);
    s += xp[k] * sg;
  }
  out[idx] = s + bias[col];
}

extern "C" void kernel_launch(void* const* d_in, const int* in_sizes, int n_in,
                              void* d_out, int out_size, void* d_ws, size_t ws_size,
                              hipStream_t stream) {
  const float* x    = (const float*)d_in[0];
  const float* w    = (const float*)d_in[1];
  const float* bias = (const float*)d_in[2];
  float* out = (float*)d_out;

  const size_t xq_bytes = (size_t)M_TOK * K_IN;           // 32 MiB
  const size_t wq_bytes = (size_t)N_OUT * K_IN;           // 16 MiB
  const size_t sc_bytes = (size_t)M_TOK * sizeof(float);  // 32 KiB

  if (ws_size < xq_bytes + wq_bytes + sc_bytes) {
    int total = M_TOK * N_OUT;
    fallback_gemm<<<(total + 255) / 256, 256, 0, stream>>>(x, w, bias, out);
    return;
  }

  char*  xq = (char*)d_ws;
  char*  wq = (char*)d_ws + xq_bytes;
  float* sc = (float*)((char*)d_ws + xq_bytes + wq_bytes);

  quant_x_i8<<<M_TOK, 256, 0, stream>>>(x, xq, sc);
  quant_w_sign<<<(N_OUT * K_IN / 4) / 1024, 256, 0, stream>>>(w, wq);

  dim3 grid(N_OUT / BN, M_TOK / BM);  // 32 x 64 = 2048 blocks
  gemm_bin_i8<<<grid, 256, 0, stream>>>(xq, wq, sc, bias, out);
}